// Round 3
// baseline (800.264 us; speedup 1.0000x reference)
//
#include <hip/hip_runtime.h>
#include <hip/hip_bf16.h>

#define B_   1024
#define T_   50
#define H_   128
#define N3_  384
#define V1_  100001
#define BT_  (B_ * T_)   // 51200

typedef __attribute__((ext_vector_type(8))) __bf16 bf16x8;
typedef __attribute__((ext_vector_type(4))) float  f32x4;

#define MFMA(a, b, c) __builtin_amdgcn_mfma_f32_16x16x32_bf16((a), (b), (c), 0, 0, 0)

// ---------------------------------------------------------------------------
// Kernel 1: xp[bt][0..384) = emb[ids[bt]] @ gru_kernel + b_i   (split-bf16 MFMA)
// grid 800 x 256 threads (4 waves). Block tile: 64 rows x 384 cols, K=128.
// ---------------------------------------------------------------------------
__global__ __launch_bounds__(256) void xp_gemm(const int* __restrict__ ids,
                                               const float* __restrict__ emb,
                                               const float* __restrict__ kern,
                                               const float* __restrict__ bias,
                                               float* __restrict__ xp) {
    __shared__ __bf16 Ah[64 * 136], Al[64 * 136];   // gathered x, split, stride 136 (pad)
    __shared__ __bf16 Bh[N3_ * 40], Bl[N3_ * 40];   // kernel chunk [n][32k], stride 40

    const int tid  = threadIdx.x;
    const int lane = tid & 63;
    const int wave = tid >> 6;
    const int lo16 = lane & 15;
    const int grp  = lane >> 4;
    const int row0 = blockIdx.x * 64;

    // stage A: gather 64 rows x 128 f32, split to hi/lo bf16
#pragma unroll
    for (int i = 0; i < 8; ++i) {
        int idx = tid + (i << 8);            // [0, 2048) float4 units
        int r   = idx >> 5;
        int c4  = (idx & 31) << 2;
        int id  = ids[row0 + r];
        f32x4 v = *reinterpret_cast<const f32x4*>(emb + (size_t)id * H_ + c4);
#pragma unroll
        for (int q = 0; q < 4; ++q) {
            __bf16 h = (__bf16)v[q];
            Ah[r * 136 + c4 + q] = h;
            Al[r * 136 + c4 + q] = (__bf16)(v[q] - (float)h);
        }
    }

    f32x4 acc[24];
#pragma unroll
    for (int ct = 0; ct < 24; ++ct) acc[ct] = (f32x4){0.f, 0.f, 0.f, 0.f};

    const int arow = wave * 16 + lo16;
    const int k0g  = grp << 3;   // 0,8,16,24 within 32-k chunk

    for (int kc = 0; kc < 4; ++kc) {
        __syncthreads();
        // stage B chunk: kern[kc*32 .. +32)[0..384) -> transposed [n][k] split
#pragma unroll
        for (int i = 0; i < 12; ++i) {
            int idx = tid + (i << 8);        // [0, 3072) float4 units over [32][96]
            int kk  = idx / 96;
            int n4  = (idx - kk * 96) << 2;
            f32x4 v = *reinterpret_cast<const f32x4*>(kern + (kc * 32 + kk) * N3_ + n4);
#pragma unroll
            for (int q = 0; q < 4; ++q) {
                __bf16 h = (__bf16)v[q];
                Bh[(n4 + q) * 40 + kk] = h;
                Bl[(n4 + q) * 40 + kk] = (__bf16)(v[q] - (float)h);
            }
        }
        __syncthreads();

        bf16x8 ah = *reinterpret_cast<const bf16x8*>(&Ah[arow * 136 + kc * 32 + k0g]);
        bf16x8 al = *reinterpret_cast<const bf16x8*>(&Al[arow * 136 + kc * 32 + k0g]);
#pragma unroll
        for (int ct = 0; ct < 24; ++ct) {
            bf16x8 bh = *reinterpret_cast<const bf16x8*>(&Bh[(ct * 16 + lo16) * 40 + k0g]);
            bf16x8 bl = *reinterpret_cast<const bf16x8*>(&Bl[(ct * 16 + lo16) * 40 + k0g]);
            acc[ct] = MFMA(ah, bh, acc[ct]);
            acc[ct] = MFMA(al, bh, acc[ct]);
            acc[ct] = MFMA(ah, bl, acc[ct]);
        }
    }

    // epilogue: D col = lane&15, row = 4*grp + reg (m89-verified layout)
#pragma unroll
    for (int ct = 0; ct < 24; ++ct) {
        int col  = ct * 16 + lo16;
        float bi = bias[col];
#pragma unroll
        for (int r = 0; r < 4; ++r) {
            int row = row0 + wave * 16 + (grp << 2) + r;
            xp[(size_t)row * N3_ + col] = acc[ct][r] + bi;
        }
    }
}

// ---------------------------------------------------------------------------
// Kernel 2: GRU scan. grid 64 x 512 threads (8 waves); block owns 16 batch rows.
// rec_kernel split-fragments live in registers; wave w owns cols {16w, 128+16w,
// 256+16w} so z/r/hcand for (m,j) land in one lane -> gates fully in registers.
// h double-buffered in LDS (one barrier per step); h also kept in registers.
// ---------------------------------------------------------------------------
__global__ __launch_bounds__(512) void gru_scan(const float* __restrict__ xp,
                                                const float* __restrict__ reck,
                                                const float* __restrict__ bias,
                                                const int* __restrict__ mask,
                                                __bf16* __restrict__ lhh,
                                                __bf16* __restrict__ lhl) {
    __shared__ __bf16 hAh[2][16 * 136];
    __shared__ __bf16 hAl[2][16 * 136];

    const int tid  = threadIdx.x;
    const int lane = tid & 63;
    const int wave = tid >> 6;
    const int lo16 = lane & 15;
    const int grp  = lane >> 4;
    const int row0 = blockIdx.x * 16;
    const int jcol = wave * 16 + lo16;     // j in [0,128)

    // preload rec_kernel fragments (split) into registers: g=0:z  1:r  2:hcand
    bf16x8 BH[3][4], BL[3][4];
#pragma unroll
    for (int g = 0; g < 3; ++g) {
        int col = g * 128 + jcol;
#pragma unroll
        for (int kc = 0; kc < 4; ++kc) {
            bf16x8 h8, l8;
#pragma unroll
            for (int e = 0; e < 8; ++e) {
                int k   = kc * 32 + (grp << 3) + e;
                float v = reck[k * N3_ + col];
                __bf16 h = (__bf16)v;
                h8[e] = h;
                l8[e] = (__bf16)(v - (float)h);
            }
            BH[g][kc] = h8;
            BL[g][kc] = l8;
        }
    }

    const float brz = bias[N3_ + jcol];
    const float brr = bias[N3_ + 128 + jcol];
    const float brh = bias[N3_ + 256 + jcol];

    // sequence lengths for my 4 rows (m = 4*grp + r)
    int len[4];
#pragma unroll
    for (int r = 0; r < 4; ++r) {
        int m = (grp << 2) + r;
        int s = 0;
        for (int t = 0; t < T_; ++t) s += mask[(row0 + m) * T_ + t];
        len[r] = s;
    }

    for (int i = tid; i < 16 * 136; i += 512) {
        hAh[0][i] = (__bf16)0.f; hAl[0][i] = (__bf16)0.f;
        hAh[1][i] = (__bf16)0.f; hAl[1][i] = (__bf16)0.f;
    }
    __syncthreads();

    float hreg[4] = {0.f, 0.f, 0.f, 0.f};
    int cur = 0;

    for (int t = 0; t < T_; ++t) {
        // prefetch xp for this step (consumed after the MFMAs -> latency hidden)
        float pz[4], pr[4], ph[4];
#pragma unroll
        for (int r = 0; r < 4; ++r) {
            int m = (grp << 2) + r;
            const float* p = xp + ((size_t)(row0 + m) * T_ + t) * N3_ + jcol;
            pz[r] = p[0];
            pr[r] = p[128];
            ph[r] = p[256];
        }

        f32x4 az = {0.f, 0.f, 0.f, 0.f};
        f32x4 ar = {0.f, 0.f, 0.f, 0.f};
        f32x4 ac = {0.f, 0.f, 0.f, 0.f};
#pragma unroll
        for (int kc = 0; kc < 4; ++kc) {
            bf16x8 fh = *reinterpret_cast<const bf16x8*>(&hAh[cur][lo16 * 136 + kc * 32 + (grp << 3)]);
            bf16x8 fl = *reinterpret_cast<const bf16x8*>(&hAl[cur][lo16 * 136 + kc * 32 + (grp << 3)]);
            az = MFMA(fh, BH[0][kc], az); az = MFMA(fl, BH[0][kc], az); az = MFMA(fh, BL[0][kc], az);
            ar = MFMA(fh, BH[1][kc], ar); ar = MFMA(fl, BH[1][kc], ar); ar = MFMA(fh, BL[1][kc], ar);
            ac = MFMA(fh, BH[2][kc], ac); ac = MFMA(fl, BH[2][kc], ac); ac = MFMA(fh, BL[2][kc], ac);
        }

        int nxt = cur ^ 1;
#pragma unroll
        for (int r = 0; r < 4; ++r) {
            int m = (grp << 2) + r;
            float z  = __fdividef(1.f, 1.f + __expf(-(pz[r] + az[r] + brz)));
            float rg = __fdividef(1.f, 1.f + __expf(-(pr[r] + ar[r] + brr)));
            float pre = ph[r] + rg * (ac[r] + brh);          // xh + r*(rec_h + b_rh)
            float e2  = __expf(2.f * fabsf(pre));
            float th  = copysignf(1.f - __fdividef(2.f, e2 + 1.f), pre);
            float hnew = z * hreg[r] + (1.f - z) * th;
            hreg[r] = hnew;
            __bf16 h16 = (__bf16)hnew;
            __bf16 l16 = (__bf16)(hnew - (float)h16);
            hAh[nxt][m * 136 + jcol] = h16;
            hAl[nxt][m * 136 + jcol] = l16;
            if (t + 1 == len[r]) {
                lhh[(size_t)(row0 + m) * H_ + jcol] = h16;
                lhl[(size_t)(row0 + m) * H_ + jcol] = l16;
            }
        }
        __syncthreads();
        cur ^= 1;
    }
}

// ---------------------------------------------------------------------------
// Kernel 3: logits[1024][100001] = last_h @ emb^T  (split-bf16 MFMA)
// grid 782 x 512 threads (8 waves). Block: 128 output cols, loops 16 chunks of
// 64 rows. B tile (emb rows, split) staged once in LDS, fragments hoisted to
// registers; A fragments loaded directly from L2-resident last_h.
// ---------------------------------------------------------------------------
__global__ __launch_bounds__(512) void logits_gemm(const __bf16* __restrict__ lhh,
                                                   const __bf16* __restrict__ lhl,
                                                   const float* __restrict__ emb,
                                                   float* __restrict__ out) {
    __shared__ __bf16 Bh[128 * 136];
    __shared__ __bf16 Bl[128 * 136];

    const int tid  = threadIdx.x;
    const int lane = tid & 63;
    const int wave = tid >> 6;
    const int lo16 = lane & 15;
    const int grp  = lane >> 4;
    const int n0   = blockIdx.x * 128;

    // stage B: emb rows n0..n0+127 (guarded), split to hi/lo
#pragma unroll
    for (int i = 0; i < 8; ++i) {
        int idx = tid + (i << 9);            // [0, 4096) float4 units over [128][32]
        int r   = idx >> 5;
        int c4  = (idx & 31) << 2;
        int n   = n0 + r;
        f32x4 v = {0.f, 0.f, 0.f, 0.f};
        if (n < V1_) v = *reinterpret_cast<const f32x4*>(emb + (size_t)n * H_ + c4);
#pragma unroll
        for (int q = 0; q < 4; ++q) {
            __bf16 h = (__bf16)v[q];
            Bh[r * 136 + c4 + q] = h;
            Bl[r * 136 + c4 + q] = (__bf16)(v[q] - (float)h);
        }
    }
    __syncthreads();

    const int wm = wave >> 1;   // row sub-tile (0..3)
    const int wn = wave & 1;    // col half (0..1)
    const int k0g = grp << 3;

    // hoist B fragments into registers (reused for all 16 M-chunks)
    bf16x8 BHr[4][4], BLr[4][4];
#pragma unroll
    for (int ct = 0; ct < 4; ++ct) {
        int rloc = wn * 64 + ct * 16 + lo16;
#pragma unroll
        for (int kc = 0; kc < 4; ++kc) {
            BHr[ct][kc] = *reinterpret_cast<const bf16x8*>(&Bh[rloc * 136 + kc * 32 + k0g]);
            BLr[ct][kc] = *reinterpret_cast<const bf16x8*>(&Bl[rloc * 136 + kc * 32 + k0g]);
        }
    }

    for (int mc = 0; mc < 16; ++mc) {
        const int mrow0 = mc * 64 + wm * 16;
        f32x4 acc[4];
#pragma unroll
        for (int ct = 0; ct < 4; ++ct) acc[ct] = (f32x4){0.f, 0.f, 0.f, 0.f};

#pragma unroll
        for (int kc = 0; kc < 4; ++kc) {
            int arow = mrow0 + lo16;
            bf16x8 ah = *reinterpret_cast<const bf16x8*>(lhh + (size_t)arow * H_ + kc * 32 + k0g);
            bf16x8 al = *reinterpret_cast<const bf16x8*>(lhl + (size_t)arow * H_ + kc * 32 + k0g);
#pragma unroll
            for (int ct = 0; ct < 4; ++ct) {
                acc[ct] = MFMA(ah, BHr[ct][kc], acc[ct]);
                acc[ct] = MFMA(al, BHr[ct][kc], acc[ct]);
                acc[ct] = MFMA(ah, BLr[ct][kc], acc[ct]);
            }
        }

#pragma unroll
        for (int ct = 0; ct < 4; ++ct) {
            int n = n0 + wn * 64 + ct * 16 + lo16;
            if (n < V1_) {
#pragma unroll
                for (int r = 0; r < 4; ++r) {
                    int m = mrow0 + (grp << 2) + r;
                    out[(size_t)m * V1_ + n] = acc[ct][r];
                }
            }
        }
    }
}

// ---------------------------------------------------------------------------
extern "C" void kernel_launch(void* const* d_in, const int* in_sizes, int n_in,
                              void* d_out, int out_size, void* d_ws, size_t ws_size,
                              hipStream_t stream) {
    const int*   ids  = (const int*)d_in[0];
    const int*   mask = (const int*)d_in[1];
    const float* emb  = (const float*)d_in[2];
    const float* kern = (const float*)d_in[3];
    const float* reck = (const float*)d_in[4];
    const float* bias = (const float*)d_in[5];
    float* out = (float*)d_out;

    // workspace layout: xp f32 [51200][384] (78,643,200 B) | last_h hi | last_h lo
    const size_t XP_BYTES = (size_t)BT_ * N3_ * 4;
    float*  xp  = (float*)d_ws;
    __bf16* lhh = (__bf16*)((char*)d_ws + XP_BYTES);
    __bf16* lhl = lhh + (size_t)B_ * H_;

    xp_gemm<<<BT_ / 64, 256, 0, stream>>>(ids, emb, kern, bias, xp);
    gru_scan<<<B_ / 16, 512, 0, stream>>>(xp, reck, bias, mask, lhh, lhl);
    logits_gemm<<<(V1_ + 127) / 128, 512, 0, stream>>>(lhh, lhl, emb, out);
}